// Round 6
// baseline (380.582 us; speedup 1.0000x reference)
//
#include <hip/hip_runtime.h>
#include <hip/hip_bf16.h>

#define D_MODEL 768
#define N_HEADS 12
#define D_K     64
#define NEG_INF (-1e9f)
#define SCALE_Q 0.1803368801111154f  // 0.125 * log2(e): exp2-domain softmax
#define W_ELEMS (D_MODEL * D_MODEL)
#define PS_PAD  40    // Ps row stride (shorts): 80 B, 16B-aligned, conflict-spread
#define RED_PAD 68    // red row stride (floats): 272 B

typedef __attribute__((ext_vector_type(8))) short          bf16x8;
typedef __attribute__((ext_vector_type(4))) float          floatx4;
typedef __attribute__((ext_vector_type(4))) unsigned short ushortx4;
typedef __attribute__((ext_vector_type(2))) unsigned int   uintx2;

static __device__ __forceinline__ unsigned short f2bf(float f) {
    unsigned u = __builtin_bit_cast(unsigned, f);
    u += 0x7FFFu + ((u >> 16) & 1u);
    return (unsigned short)(u >> 16);
}

// async 16B/lane global->LDS (lds dest = wave-uniform base + lane*16)
static __device__ __forceinline__ void gload_lds16(const void* g, void* l) {
    __builtin_amdgcn_global_load_lds(
        (const __attribute__((address_space(1))) void*)g,
        (__attribute__((address_space(3))) void*)l, 16, 0, 0);
}

// ---------------------------------------------------------------------------
// fp32 -> bf16 converters.
// ---------------------------------------------------------------------------
__global__ __launch_bounds__(256) void convert_w4(
    const float* __restrict__ W0, const float* __restrict__ W1,
    const float* __restrict__ W2, const float* __restrict__ W3,
    unsigned short* __restrict__ out)
{
    const float* src[4] = {W0, W1, W2, W3};
    const float* W = src[blockIdx.y];
    unsigned short* o = out + (size_t)blockIdx.y * W_ELEMS;
    const int i = (blockIdx.x * 256 + threadIdx.x) * 4;
    float4 v = *(const float4*)(W + i);
    ushortx4 h = { f2bf(v.x), f2bf(v.y), f2bf(v.z), f2bf(v.w) };
    *(ushortx4*)(o + i) = h;
}

__global__ __launch_bounds__(256) void convert_a3(
    const float* __restrict__ A0, const float* __restrict__ A1,
    const float* __restrict__ A2,
    unsigned short* __restrict__ O0, unsigned short* __restrict__ O1,
    unsigned short* __restrict__ O2)
{
    const int z = blockIdx.y;
    const float* A = (z == 0) ? A0 : (z == 1) ? A1 : A2;
    unsigned short* O = (z == 0) ? O0 : (z == 1) ? O1 : O2;
    const int i = (blockIdx.x * 256 + threadIdx.x) * 4;
    float4 v = *(const float4*)(A + i);
    ushortx4 h = { f2bf(v.x), f2bf(v.y), f2bf(v.z), f2bf(v.w) };
    *(ushortx4*)(O + i) = h;
}

// ---------------------------------------------------------------------------
// C[M,N] = A[M,K] @ W[N,K]^T + bias[N];  A, W bf16; K = N = 768.
// m97 shape: 128x128 block tile, BK=32, 4 waves in 2x2 (64x64/wave),
// acc[4][4] -> 32 MFMA per barrier pair. Async global_load_lds staging.
// ---------------------------------------------------------------------------
template <bool QKV>
__global__ __launch_bounds__(256) void gemm128(
    const unsigned short* __restrict__ A0, const unsigned short* __restrict__ A1,
    const unsigned short* __restrict__ A2,
    const unsigned short* __restrict__ W0, const unsigned short* __restrict__ W1,
    const unsigned short* __restrict__ W2,
    const float* __restrict__ b0, const float* __restrict__ b1,
    const float* __restrict__ b2,
    void* __restrict__ C0, void* __restrict__ C1, void* __restrict__ C2,
    int S)
{
    __shared__ __align__(16) unsigned short As[128 * 32];
    __shared__ __align__(16) unsigned short Bs[128 * 32];

    const int z = QKV ? blockIdx.z : 0;
    const unsigned short* A = (z == 0) ? A0 : (z == 1) ? A1 : A2;
    const unsigned short* W = (z == 0) ? W0 : (z == 1) ? W1 : W2;
    const float* bias       = (z == 0) ? b0 : (z == 1) ? b1 : b2;
    void* C                 = (z == 0) ? C0 : (z == 1) ? C1 : C2;
    const float scale = (QKV && z == 0) ? SCALE_Q : 1.0f;
    const int mode = QKV ? ((z == 2) ? 3 : 1) : 0;   // 3=VpT, 1=bf16, 0=fp32

    const int tid  = threadIdx.x;
    const int wave = tid >> 6;
    const int lane = tid & 63;
    const int quad = lane >> 4;
    const int l16  = lane & 15;
    const int m0 = blockIdx.x * 128;
    const int n0 = blockIdx.y * 128;
    const int wm = (wave & 1) * 64;
    const int wn = (wave >> 1) * 64;
    const int sr = lane >> 2;          // staging row within 16-row group
    const int sc = (lane & 3) << 3;    // staging col chunk (8 shorts = 16 B)

    const floatx4 zero4 = {0.f, 0.f, 0.f, 0.f};
    floatx4 acc[4][4];
    #pragma unroll
    for (int i = 0; i < 4; ++i)
        #pragma unroll
        for (int j = 0; j < 4; ++j) acc[i][j] = zero4;

    for (int k0 = 0; k0 < D_MODEL; k0 += 32) {
        #pragma unroll
        for (int c = 0; c < 2; ++c) {
            const int row = wave * 32 + c * 16;
            gload_lds16(A + (size_t)(m0 + row + sr) * D_MODEL + k0 + sc,
                        As + row * 32);
            gload_lds16(W + (size_t)(n0 + row + sr) * D_MODEL + k0 + sc,
                        Bs + row * 32);
        }
        __syncthreads();

        bf16x8 af[4], bfr[4];
        #pragma unroll
        for (int i = 0; i < 4; ++i)
            af[i] = *(const bf16x8*)(As + (wm + i * 16 + l16) * 32 + quad * 8);
        #pragma unroll
        for (int j = 0; j < 4; ++j)
            bfr[j] = *(const bf16x8*)(Bs + (wn + j * 16 + l16) * 32 + quad * 8);
        #pragma unroll
        for (int i = 0; i < 4; ++i)
            #pragma unroll
            for (int j = 0; j < 4; ++j)
                acc[i][j] = __builtin_amdgcn_mfma_f32_16x16x32_bf16(
                    bfr[j], af[i], acc[i][j], 0, 0, 0);   // swapped: rows=n
        __syncthreads();
    }

    // epilogue: D[i][j] rows (quad*4+r) = n, cols (l16) = m
    #pragma unroll
    for (int i = 0; i < 4; ++i) {
        const int m = m0 + wm + i * 16 + l16;
        #pragma unroll
        for (int j = 0; j < 4; ++j) {
            const int nb = n0 + wn + j * 16 + quad * 4;
            const float4 bv = *(const float4*)(bias + nb);
            float v0 = (acc[i][j][0] + bv.x) * scale;
            float v1 = (acc[i][j][1] + bv.y) * scale;
            float v2 = (acc[i][j][2] + bv.z) * scale;
            float v3 = (acc[i][j][3] + bv.w) * scale;
            if (mode == 0) {
                float4 o = {v0, v1, v2, v3};
                *(float4*)((float*)C + (size_t)m * D_MODEL + nb) = o;
            } else if (mode == 1) {
                ushortx4 o = {f2bf(v0), f2bf(v1), f2bf(v2), f2bf(v3)};
                *(ushortx4*)((unsigned short*)C + (size_t)m * D_MODEL + nb) = o;
            } else {
                const int bb = m / S, s = m - bb * S;
                const int hh = nb >> 6, d = nb & 63;
                unsigned short* base = (unsigned short*)C +
                    ((size_t)(bb * N_HEADS + hh) * D_K + d) * S + s;
                base[0]             = f2bf(v0);
                base[(size_t)S]     = f2bf(v1);
                base[(size_t)S * 2] = f2bf(v2);
                base[(size_t)S * 3] = f2bf(v3);
            }
        }
    }
}

// ---------------------------------------------------------------------------
// Causal flash attention, keys-split-across-waves, barrier-free k-loop.
// Block: 64 q-rows (paired tiles p, 63-p -> 33 uniform 128-key iterations).
// Wave w owns key slice [k0+32w, k0+32w+32): loads its K/V fragments straight
// from L2 into registers (disjoint across waves -> no duplication, no LDS
// staging). qf (4 qg x 2 kh) lives in registers across the whole k-loop.
// Only LDS in-loop: wave-local P transpose (C-layout -> A-operand).
// Each wave accumulates partial O (64q x 64d) + partial l over its slice;
// pairwise LDS reduction per sel (LDS union-aliased with Ps).
// ---------------------------------------------------------------------------
union FlashSmem {
    unsigned short Ps[4][64 * PS_PAD];                      // k-loop, wave-local
    struct { float red[2][64 * RED_PAD]; float redl[2][64]; } ep;  // epilogue
};

__global__ __launch_bounds__(256, 3) void flash_attn(
    const unsigned short* __restrict__ Qp,
    const unsigned short* __restrict__ Kp,
    const unsigned short* __restrict__ VpT,
    const int* __restrict__ mask,
    unsigned short* __restrict__ O,   // bf16 [B*S, D_MODEL]
    int S)
{
    __shared__ __align__(16) FlashSmem sm;

    const int L  = blockIdx.x;
    const int bh = L % 24;
    const int p  = L / 24;
    const int h  = bh % 12;
    const int b  = bh / 12;
    const int nqt = S >> 6;
    const int tid  = threadIdx.x;
    const int wave = tid >> 6;
    const int lane = tid & 63;
    const int quad = lane >> 4;
    const int l16  = lane & 15;
    const int ksl  = wave * 32;          // this wave's key-slice offset in tile

    const unsigned short* Kbase = Kp  + (size_t)(b * S) * D_MODEL + h * D_K;
    const unsigned short* Vbase = VpT + (size_t)(b * N_HEADS + h) * D_K * S;
    const int* maskb = mask + b * S;
    unsigned short* Psw = sm.Ps[wave];

    const floatx4 zero4 = {0.f, 0.f, 0.f, 0.f};
    const short one_bf = (short)0x3F80;  // bf16 1.0
    const bf16x8 ones = {one_bf, one_bf, one_bf, one_bf,
                         one_bf, one_bf, one_bf, one_bf};

    #pragma unroll
    for (int sel = 0; sel < 2; ++sel) {
        const int qt = sel ? (nqt - 1 - p) : p;
        const int q0 = qt * 64;

        // Q fragments (B-operand: n=q=l16, k=quad*8+j), held for whole k-loop
        bf16x8 qf[4][2];
        #pragma unroll
        for (int qg = 0; qg < 4; ++qg) {
            const size_t rowQ = (size_t)(b * S + q0 + qg * 16 + l16) * D_MODEL + h * D_K;
            qf[qg][0] = *(const bf16x8*)(Qp + rowQ + quad * 8);
            qf[qg][1] = *(const bf16x8*)(Qp + rowQ + 32 + quad * 8);
        }

        floatx4 acc2[4][4];   // [qg][dt]: q=qg*16+quad*4+r, d=dt*16+l16
        floatx4 acc_l[4];     // [qg]:    q=qg*16+quad*4+r (dup across l16)
        #pragma unroll
        for (int qg = 0; qg < 4; ++qg) {
            acc_l[qg] = zero4;
            #pragma unroll
            for (int dt = 0; dt < 4; ++dt) acc2[qg][dt] = zero4;
        }

        const int ni = (qt >> 1) + 1;
        for (int kt = 0; kt < ni; ++kt) {
            const int kb = kt * 128 + ksl;       // slice's first key
            if (kb > q0 + 63) continue;          // wave-uniform: fully masked
            const bool last = (kt == ni - 1);

            // K fragments (A-operand: m=key=l16, k=quad*8+j) — direct from L2
            bf16x8 kf[2][2];
            #pragma unroll
            for (int ntg = 0; ntg < 2; ++ntg) {
                const size_t rowK = (size_t)(kb + ntg * 16 + l16) * D_MODEL;
                kf[ntg][0] = *(const bf16x8*)(Kbase + rowK + quad * 8);
                kf[ntg][1] = *(const bf16x8*)(Kbase + rowK + 32 + quad * 8);
            }
            // V fragments (B-operand: n=d=l16, k=key=quad*8+j) — direct from L2
            bf16x8 vf[4];
            #pragma unroll
            for (int dt = 0; dt < 4; ++dt)
                vf[dt] = *(const bf16x8*)(Vbase + (size_t)(dt * 16 + l16) * S + kb + quad * 8);

            // padding-mask init (int4 broadcast per ntg)
            #pragma unroll
            for (int ntg = 0; ntg < 2; ++ntg) {
                const int4 mv = *(const int4*)(maskb + kb + ntg * 16 + quad * 4);
                floatx4 minit;
                minit[0] = (mv.x == 0) ? NEG_INF : 0.f;
                minit[1] = (mv.y == 0) ? NEG_INF : 0.f;
                minit[2] = (mv.z == 0) ? NEG_INF : 0.f;
                minit[3] = (mv.w == 0) ? NEG_INF : 0.f;

                // S^T tiles: rows=key(quad*4+r), cols=q(l16)
                #pragma unroll
                for (int qg = 0; qg < 4; ++qg) {
                    floatx4 c = minit;
                    c = __builtin_amdgcn_mfma_f32_16x16x32_bf16(kf[ntg][0], qf[qg][0], c, 0, 0, 0);
                    c = __builtin_amdgcn_mfma_f32_16x16x32_bf16(kf[ntg][1], qf[qg][1], c, 0, 0, 0);
                    if (last) {
                        const int kk = kb + ntg * 16 + quad * 4;
                        const int qq = q0 + qg * 16 + l16;
                        #pragma unroll
                        for (int r = 0; r < 4; ++r)
                            if (kk + r > qq) c[r] = NEG_INF;
                    }
                    // P = exp2(s), truncation-packed (bias cancels in O=PV/l)
                    const float e0 = __builtin_exp2f(c[0]);
                    const float e1 = __builtin_exp2f(c[1]);
                    const float e2 = __builtin_exp2f(c[2]);
                    const float e3 = __builtin_exp2f(c[3]);
                    uintx2 pk;
                    pk[0] = __builtin_amdgcn_perm(__builtin_bit_cast(unsigned, e1),
                                                  __builtin_bit_cast(unsigned, e0), 0x07060302u);
                    pk[1] = __builtin_amdgcn_perm(__builtin_bit_cast(unsigned, e3),
                                                  __builtin_bit_cast(unsigned, e2), 0x07060302u);
                    *(uintx2*)(Psw + (qg * 16 + l16) * PS_PAD + ntg * 16 + quad * 4) = pk;
                }
            }

            // O_partial += P V ; l_partial += P 1  (K=32 = this wave's slice)
            #pragma unroll
            for (int qg = 0; qg < 4; ++qg) {
                const bf16x8 pf = *(const bf16x8*)(Psw + (qg * 16 + l16) * PS_PAD + quad * 8);
                #pragma unroll
                for (int dt = 0; dt < 4; ++dt)
                    acc2[qg][dt] = __builtin_amdgcn_mfma_f32_16x16x32_bf16(
                        pf, vf[dt], acc2[qg][dt], 0, 0, 0);
                acc_l[qg] = __builtin_amdgcn_mfma_f32_16x16x32_bf16(
                    pf, ones, acc_l[qg], 0, 0, 0);
            }
        }

        // ---- cross-wave reduction of partial O, l (pairwise via LDS) ----
        __syncthreads();   // all waves done with Ps (aliased by red)
        if (wave >= 2) {
            float* rb = sm.ep.red[wave - 2];
            #pragma unroll
            for (int qg = 0; qg < 4; ++qg) {
                #pragma unroll
                for (int dt = 0; dt < 4; ++dt)
                    *(floatx4*)(rb + (dt * 16 + l16) * RED_PAD + qg * 16 + quad * 4) = acc2[qg][dt];
                if (l16 == 0)
                    *(floatx4*)(sm.ep.redl[wave - 2] + qg * 16 + quad * 4) = acc_l[qg];
            }
        }
        __syncthreads();
        if (wave < 2) {
            const float* rb = sm.ep.red[wave];
            #pragma unroll
            for (int qg = 0; qg < 4; ++qg) {
                #pragma unroll
                for (int dt = 0; dt < 4; ++dt)
                    acc2[qg][dt] += *(const floatx4*)(rb + (dt * 16 + l16) * RED_PAD + qg * 16 + quad * 4);
                acc_l[qg] += *(const floatx4*)(sm.ep.redl[wave] + qg * 16 + quad * 4);
            }
        }
        __syncthreads();
        if (wave == 1) {
            float* rb = sm.ep.red[0];
            #pragma unroll
            for (int qg = 0; qg < 4; ++qg) {
                #pragma unroll
                for (int dt = 0; dt < 4; ++dt)
                    *(floatx4*)(rb + (dt * 16 + l16) * RED_PAD + qg * 16 + quad * 4) = acc2[qg][dt];
                if (l16 == 0)
                    *(floatx4*)(sm.ep.redl[0] + qg * 16 + quad * 4) = acc_l[qg];
            }
        }
        __syncthreads();
        if (wave == 0) {
            const float* rb = sm.ep.red[0];
            #pragma unroll
            for (int qg = 0; qg < 4; ++qg) {
                acc_l[qg] += *(const floatx4*)(sm.ep.redl[0] + qg * 16 + quad * 4);
                #pragma unroll
                for (int dt = 0; dt < 4; ++dt)
                    acc2[qg][dt] += *(const floatx4*)(rb + (dt * 16 + l16) * RED_PAD + qg * 16 + quad * 4);
                #pragma unroll
                for (int r = 0; r < 4; ++r) {
                    const float inv = 1.f / acc_l[qg][r];
                    const int gq = q0 + qg * 16 + quad * 4 + r;
                    unsigned short* ob = O + (size_t)(b * S + gq) * D_MODEL + h * D_K;
                    #pragma unroll
                    for (int dt = 0; dt < 4; ++dt)
                        ob[dt * 16 + l16] = f2bf(acc2[qg][dt][r] * inv);
                }
            }
        }
        __syncthreads();   // red dead before next sel's Ps writes
    }
}

// ---------------------------------------------------------------------------
extern "C" void kernel_launch(void* const* d_in, const int* in_sizes, int n_in,
                              void* d_out, int out_size, void* d_ws, size_t ws_size,
                              hipStream_t stream) {
    const float* query = (const float*)d_in[0];
    const float* key   = (const float*)d_in[1];
    const float* value = (const float*)d_in[2];
    const int*   mask  = (const int*)d_in[3];
    const float* Wq = (const float*)d_in[4];
    const float* bq = (const float*)d_in[5];
    const float* Wk = (const float*)d_in[6];
    const float* bk = (const float*)d_in[7];
    const float* Wv = (const float*)d_in[8];
    const float* bv = (const float*)d_in[9];
    const float* Wo = (const float*)d_in[10];
    const float* bo = (const float*)d_in[11];

    const int B  = 2;
    const int BS = in_sizes[3];
    const int S  = BS / B;
    const int M  = BS;

    unsigned short* Qp  = (unsigned short*)d_ws;
    unsigned short* Kp  = Qp  + (size_t)M * D_MODEL;
    unsigned short* VpT = Kp  + (size_t)M * D_MODEL;
    unsigned short* Obf = VpT + (size_t)M * D_MODEL;  // qa staging, then O
    unsigned short* Wbf = Obf + (size_t)M * D_MODEL;
    unsigned short* Wqb = Wbf;
    unsigned short* Wkb = Wbf + (size_t)W_ELEMS;
    unsigned short* Wvb = Wbf + (size_t)W_ELEMS * 2;
    unsigned short* Wob = Wbf + (size_t)W_ELEMS * 3;
    // d_out (25.2 MB fp32) doubles as scratch for ka/va bf16 until final GEMM
    unsigned short* ka = (unsigned short*)d_out;
    unsigned short* va = ka + (size_t)M * D_MODEL;

    dim3 blk(256);
    convert_w4<<<dim3(W_ELEMS / 1024, 4), blk, 0, stream>>>(Wq, Wk, Wv, Wo, Wbf);
    convert_a3<<<dim3((M * D_MODEL) / 1024, 3), blk, 0, stream>>>(
        query, key, value, Obf, ka, va);

    gemm128<true><<<dim3(M / 128, D_MODEL / 128, 3), blk, 0, stream>>>(
        Obf, ka, va, Wqb, Wkb, Wvb, bq, bk, bv, Qp, Kp, VpT, S);

    flash_attn<<<768, blk, 0, stream>>>(Qp, Kp, VpT, mask, Obf, S);

    gemm128<false><<<dim3(M / 128, D_MODEL / 128, 1), blk, 0, stream>>>(
        Obf, Obf, Obf, Wob, Wob, Wob, bo, bo, bo,
        d_out, d_out, d_out, S);
}

// Round 7
// 320.844 us; speedup vs baseline: 1.1862x; 1.1862x over previous
//
#include <hip/hip_runtime.h>
#include <hip/hip_bf16.h>

#define D_MODEL 768
#define N_HEADS 12
#define D_K     64
#define NEG_INF (-1e9f)
#define SCALE_Q 0.1803368801111154f  // 0.125 * log2(e): exp2-domain softmax
#define W_ELEMS (D_MODEL * D_MODEL)
#define PS_PAD  72    // Ps row stride (shorts): 144 B, 16B-aligned, 2-way banks
#define RED_PAD 36    // red row stride (floats): 144 B, 16B-aligned, 2-way banks

typedef __attribute__((ext_vector_type(8))) short          bf16x8;
typedef __attribute__((ext_vector_type(4))) float          floatx4;
typedef __attribute__((ext_vector_type(4))) unsigned short ushortx4;
typedef __attribute__((ext_vector_type(2))) unsigned int   uintx2;

static __device__ __forceinline__ unsigned short f2bf(float f) {
    unsigned u = __builtin_bit_cast(unsigned, f);
    u += 0x7FFFu + ((u >> 16) & 1u);
    return (unsigned short)(u >> 16);
}

// async 16B/lane global->LDS (lds dest = wave-uniform base + lane*16)
static __device__ __forceinline__ void gload_lds16(const void* g, void* l) {
    __builtin_amdgcn_global_load_lds(
        (const __attribute__((address_space(1))) void*)g,
        (__attribute__((address_space(3))) void*)l, 16, 0, 0);
}

// ---------------------------------------------------------------------------
// fp32 -> bf16 converters.
// ---------------------------------------------------------------------------
__global__ __launch_bounds__(256) void convert_w4(
    const float* __restrict__ W0, const float* __restrict__ W1,
    const float* __restrict__ W2, const float* __restrict__ W3,
    unsigned short* __restrict__ out)
{
    const float* src[4] = {W0, W1, W2, W3};
    const float* W = src[blockIdx.y];
    unsigned short* o = out + (size_t)blockIdx.y * W_ELEMS;
    const int i = (blockIdx.x * 256 + threadIdx.x) * 4;
    float4 v = *(const float4*)(W + i);
    ushortx4 h = { f2bf(v.x), f2bf(v.y), f2bf(v.z), f2bf(v.w) };
    *(ushortx4*)(o + i) = h;
}

__global__ __launch_bounds__(256) void convert_a3(
    const float* __restrict__ A0, const float* __restrict__ A1,
    const float* __restrict__ A2,
    unsigned short* __restrict__ O0, unsigned short* __restrict__ O1,
    unsigned short* __restrict__ O2)
{
    const int z = blockIdx.y;
    const float* A = (z == 0) ? A0 : (z == 1) ? A1 : A2;
    unsigned short* O = (z == 0) ? O0 : (z == 1) ? O1 : O2;
    const int i = (blockIdx.x * 256 + threadIdx.x) * 4;
    float4 v = *(const float4*)(A + i);
    ushortx4 h = { f2bf(v.x), f2bf(v.y), f2bf(v.z), f2bf(v.w) };
    *(ushortx4*)(O + i) = h;
}

// ---------------------------------------------------------------------------
// C[M,N] = A[M,K] @ W[N,K]^T + bias[N];  A, W bf16; K = N = 768.  (unchanged)
// ---------------------------------------------------------------------------
template <bool QKV>
__global__ __launch_bounds__(256) void gemm128(
    const unsigned short* __restrict__ A0, const unsigned short* __restrict__ A1,
    const unsigned short* __restrict__ A2,
    const unsigned short* __restrict__ W0, const unsigned short* __restrict__ W1,
    const unsigned short* __restrict__ W2,
    const float* __restrict__ b0, const float* __restrict__ b1,
    const float* __restrict__ b2,
    void* __restrict__ C0, void* __restrict__ C1, void* __restrict__ C2,
    int S)
{
    __shared__ __align__(16) unsigned short As[128 * 32];
    __shared__ __align__(16) unsigned short Bs[128 * 32];

    const int z = QKV ? blockIdx.z : 0;
    const unsigned short* A = (z == 0) ? A0 : (z == 1) ? A1 : A2;
    const unsigned short* W = (z == 0) ? W0 : (z == 1) ? W1 : W2;
    const float* bias       = (z == 0) ? b0 : (z == 1) ? b1 : b2;
    void* C                 = (z == 0) ? C0 : (z == 1) ? C1 : C2;
    const float scale = (QKV && z == 0) ? SCALE_Q : 1.0f;
    const int mode = QKV ? ((z == 2) ? 3 : 1) : 0;   // 3=VpT, 1=bf16, 0=fp32

    const int tid  = threadIdx.x;
    const int wave = tid >> 6;
    const int lane = tid & 63;
    const int quad = lane >> 4;
    const int l16  = lane & 15;
    const int m0 = blockIdx.x * 128;
    const int n0 = blockIdx.y * 128;
    const int wm = (wave & 1) * 64;
    const int wn = (wave >> 1) * 64;
    const int sr = lane >> 2;
    const int sc = (lane & 3) << 3;

    const floatx4 zero4 = {0.f, 0.f, 0.f, 0.f};
    floatx4 acc[4][4];
    #pragma unroll
    for (int i = 0; i < 4; ++i)
        #pragma unroll
        for (int j = 0; j < 4; ++j) acc[i][j] = zero4;

    for (int k0 = 0; k0 < D_MODEL; k0 += 32) {
        #pragma unroll
        for (int c = 0; c < 2; ++c) {
            const int row = wave * 32 + c * 16;
            gload_lds16(A + (size_t)(m0 + row + sr) * D_MODEL + k0 + sc,
                        As + row * 32);
            gload_lds16(W + (size_t)(n0 + row + sr) * D_MODEL + k0 + sc,
                        Bs + row * 32);
        }
        __syncthreads();

        bf16x8 af[4], bfr[4];
        #pragma unroll
        for (int i = 0; i < 4; ++i)
            af[i] = *(const bf16x8*)(As + (wm + i * 16 + l16) * 32 + quad * 8);
        #pragma unroll
        for (int j = 0; j < 4; ++j)
            bfr[j] = *(const bf16x8*)(Bs + (wn + j * 16 + l16) * 32 + quad * 8);
        #pragma unroll
        for (int i = 0; i < 4; ++i)
            #pragma unroll
            for (int j = 0; j < 4; ++j)
                acc[i][j] = __builtin_amdgcn_mfma_f32_16x16x32_bf16(
                    bfr[j], af[i], acc[i][j], 0, 0, 0);   // swapped: rows=n
        __syncthreads();
    }

    #pragma unroll
    for (int i = 0; i < 4; ++i) {
        const int m = m0 + wm + i * 16 + l16;
        #pragma unroll
        for (int j = 0; j < 4; ++j) {
            const int nb = n0 + wn + j * 16 + quad * 4;
            const float4 bv = *(const float4*)(bias + nb);
            float v0 = (acc[i][j][0] + bv.x) * scale;
            float v1 = (acc[i][j][1] + bv.y) * scale;
            float v2 = (acc[i][j][2] + bv.z) * scale;
            float v3 = (acc[i][j][3] + bv.w) * scale;
            if (mode == 0) {
                float4 o = {v0, v1, v2, v3};
                *(float4*)((float*)C + (size_t)m * D_MODEL + nb) = o;
            } else if (mode == 1) {
                ushortx4 o = {f2bf(v0), f2bf(v1), f2bf(v2), f2bf(v3)};
                *(ushortx4*)((unsigned short*)C + (size_t)m * D_MODEL + nb) = o;
            } else {
                const int bb = m / S, s = m - bb * S;
                const int hh = nb >> 6, d = nb & 63;
                unsigned short* base = (unsigned short*)C +
                    ((size_t)(bb * N_HEADS + hh) * D_K + d) * S + s;
                base[0]             = f2bf(v0);
                base[(size_t)S]     = f2bf(v1);
                base[(size_t)S * 2] = f2bf(v2);
                base[(size_t)S * 3] = f2bf(v3);
            }
        }
    }
}

// ---------------------------------------------------------------------------
// Causal flash attention, 2x2 wave split (qw: 32-q half, kw: 64-key half).
// Block: 64 q-rows, paired tiles (p, 63-p) -> exactly 33 uniform 128-key
// iterations. XCD swizzle bh = L%24. K and V^T staged FRAGMENT-MAJOR via
// async global_load_lds (LDS dest = frag_base + lane*16 -> all fragment
// reads are linear & conflict-free; zero staging VALU).
// Per-wave partial O (32q x 64d, 32 AGPR) + l over its key half; one LDS
// reduction per sel (buffer aliased over the K/V frag region).
// Fixed-m exp2 softmax; padding mask folded into QK accumulator init;
// row-sum l via ones-MFMA.
// ---------------------------------------------------------------------------
union FlashSmem {
    struct {
        unsigned short KsF[16 * 512];   // frag (kg 0..7, kh 0..1): 16 frags x 1KB
        unsigned short VtsF[16 * 512];  // frag (dt 0..3, kq 0..3)
    } kv;
    struct {
        float red[2][64 * RED_PAD];     // per qw: [d][q] partial O
        float redl[2][32];              // per qw: partial l
    } ep;
};

__global__ __launch_bounds__(256, 3) void flash_attn(
    const unsigned short* __restrict__ Qp,
    const unsigned short* __restrict__ Kp,
    const unsigned short* __restrict__ VpT,
    const int* __restrict__ mask,
    unsigned short* __restrict__ O,   // bf16 [B*S, D_MODEL]
    int S)
{
    __shared__ __align__(16) FlashSmem sm;
    __shared__ __align__(16) unsigned short Ps[4][32 * PS_PAD];
    __shared__ __align__(16) float mskf[128];

    const int L  = blockIdx.x;
    const int bh = L % 24;
    const int p  = L / 24;
    const int h  = bh % 12;
    const int b  = bh / 12;
    const int nqt = S >> 6;
    const int tid  = threadIdx.x;
    const int wave = tid >> 6;
    const int qw   = wave & 1;
    const int kw   = wave >> 1;
    const int lane = tid & 63;
    const int quad = lane >> 4;
    const int l16  = lane & 15;
    const int ksl  = kw * 64;          // wave's key-slice offset within tile

    const unsigned short* Kbase = Kp  + (size_t)(b * S) * D_MODEL + h * D_K;
    const unsigned short* Vbase = VpT + (size_t)(b * N_HEADS + h) * D_K * S;
    unsigned short* Psw = Ps[wave];

    const floatx4 zero4 = {0.f, 0.f, 0.f, 0.f};
    const short one_bf = (short)0x3F80;  // bf16 1.0
    const bf16x8 ones = {one_bf, one_bf, one_bf, one_bf,
                         one_bf, one_bf, one_bf, one_bf};

    #pragma unroll
    for (int sel = 0; sel < 2; ++sel) {
        const int qt = sel ? (nqt - 1 - p) : p;
        const int q0 = qt * 64;
        const int qs = q0 + qw * 32;       // wave's 32-q strip

        // Q fragments (B-operand: n=q=l16, k=quad*8+j), live across k-loop
        bf16x8 qf[2][2];
        #pragma unroll
        for (int qg = 0; qg < 2; ++qg) {
            const size_t rowQ = (size_t)(b * S + qs + qg * 16 + l16) * D_MODEL + h * D_K;
            qf[qg][0] = *(const bf16x8*)(Qp + rowQ + quad * 8);
            qf[qg][1] = *(const bf16x8*)(Qp + rowQ + 32 + quad * 8);
        }

        floatx4 accO[2][4];   // [qg][dt]: row=q(quad*4+r), col=d(l16)
        floatx4 accL[2];      // [qg]: row=q(quad*4+r), dup across l16
        #pragma unroll
        for (int qg = 0; qg < 2; ++qg) {
            accL[qg] = zero4;
            #pragma unroll
            for (int dt = 0; dt < 4; ++dt) accO[qg][dt] = zero4;
        }

        const int ni = (qt >> 1) + 1;
        for (int kt = 0; kt < ni; ++kt) {
            const int k0 = kt * 128;
            // ---- fragment-major async staging (4 K-frags + 4 V-frags per wave)
            #pragma unroll
            for (int c = 0; c < 4; ++c) {
                const int kg = wave * 2 + (c >> 1);   // 0..7
                const int kh = c & 1;
                gload_lds16(Kbase + (size_t)(k0 + kg * 16 + l16) * D_MODEL + kh * 32 + quad * 8,
                            sm.kv.KsF + (kg * 2 + kh) * 512);
                const int dt = wave;                  // 0..3
                const int kq = c;                     // 0..3
                gload_lds16(Vbase + (size_t)(dt * 16 + l16) * S + k0 + kq * 32 + quad * 8,
                            sm.kv.VtsF + (dt * 4 + kq) * 512);
            }
            if (tid < 128)
                mskf[tid] = (mask[b * S + k0 + tid] == 0) ? NEG_INF : 0.f;
            __syncthreads();

            const int kb = k0 + ksl;                  // wave slice's first key
            if (kb <= q0 + 63) {                      // wave-uniform causal skip
                const bool diag = (kb + 63 > qs);

                // S^T = K Q^T (+mask init): rows=keys(quad*4+r), cols=q(l16)
                #pragma unroll
                for (int nt = 0; nt < 4; ++nt) {
                    const floatx4 minit = *(const floatx4*)(mskf + ksl + nt * 16 + quad * 4);
                    const int kgf = (kw * 4 + nt) * 2;
                    const bf16x8 kf0 = *(const bf16x8*)(sm.kv.KsF + kgf * 512 + lane * 8);
                    const bf16x8 kf1 = *(const bf16x8*)(sm.kv.KsF + (kgf + 1) * 512 + lane * 8);
                    #pragma unroll
                    for (int qg = 0; qg < 2; ++qg) {
                        floatx4 c = minit;
                        c = __builtin_amdgcn_mfma_f32_16x16x32_bf16(kf0, qf[qg][0], c, 0, 0, 0);
                        c = __builtin_amdgcn_mfma_f32_16x16x32_bf16(kf1, qf[qg][1], c, 0, 0, 0);
                        if (diag) {
                            const int kk = kb + nt * 16 + quad * 4;
                            const int qq = qs + qg * 16 + l16;
                            #pragma unroll
                            for (int r = 0; r < 4; ++r)
                                if (kk + r > qq) c[r] = NEG_INF;
                        }
                        // P = exp2(s), truncation-packed (bias cancels in O=PV/l)
                        const float e0 = __builtin_exp2f(c[0]);
                        const float e1 = __builtin_exp2f(c[1]);
                        const float e2 = __builtin_exp2f(c[2]);
                        const float e3 = __builtin_exp2f(c[3]);
                        uintx2 pk;
                        pk[0] = __builtin_amdgcn_perm(__builtin_bit_cast(unsigned, e1),
                                                      __builtin_bit_cast(unsigned, e0), 0x07060302u);
                        pk[1] = __builtin_amdgcn_perm(__builtin_bit_cast(unsigned, e3),
                                                      __builtin_bit_cast(unsigned, e2), 0x07060302u);
                        *(uintx2*)(Psw + (qg * 16 + l16) * PS_PAD + nt * 16 + quad * 4) = pk;
                    }
                }

                // O_part += P V ; l_part += P 1  (wave's 64-key slice, 2 kh)
                #pragma unroll
                for (int kh = 0; kh < 2; ++kh) {
                    bf16x8 pf[2];
                    #pragma unroll
                    for (int qg = 0; qg < 2; ++qg)
                        pf[qg] = *(const bf16x8*)(Psw + (qg * 16 + l16) * PS_PAD + kh * 32 + quad * 8);
                    #pragma unroll
                    for (int dt = 0; dt < 4; ++dt) {
                        const bf16x8 vf = *(const bf16x8*)(
                            sm.kv.VtsF + (dt * 4 + kw * 2 + kh) * 512 + lane * 8);
                        #pragma unroll
                        for (int qg = 0; qg < 2; ++qg)
                            accO[qg][dt] = __builtin_amdgcn_mfma_f32_16x16x32_bf16(
                                pf[qg], vf, accO[qg][dt], 0, 0, 0);
                    }
                    #pragma unroll
                    for (int qg = 0; qg < 2; ++qg)
                        accL[qg] = __builtin_amdgcn_mfma_f32_16x16x32_bf16(
                            pf[qg], ones, accL[qg], 0, 0, 0);
                }
            }
            __syncthreads();
        }

        // ---- cross-kw reduction + epilogue (red aliased over K/V frags) ----
        if (kw == 1) {
            float* rb = sm.ep.red[qw];
            #pragma unroll
            for (int qg = 0; qg < 2; ++qg) {
                #pragma unroll
                for (int dt = 0; dt < 4; ++dt)
                    *(floatx4*)(rb + (dt * 16 + l16) * RED_PAD + qg * 16 + quad * 4) = accO[qg][dt];
                if (l16 == 0)
                    *(floatx4*)(sm.ep.redl[qw] + qg * 16 + quad * 4) = accL[qg];
            }
        }
        __syncthreads();
        if (kw == 0) {
            const float* rb = sm.ep.red[qw];
            #pragma unroll
            for (int qg = 0; qg < 2; ++qg) {
                accL[qg] += *(const floatx4*)(sm.ep.redl[qw] + qg * 16 + quad * 4);
                #pragma unroll
                for (int dt = 0; dt < 4; ++dt)
                    accO[qg][dt] += *(const floatx4*)(rb + (dt * 16 + l16) * RED_PAD + qg * 16 + quad * 4);
                #pragma unroll
                for (int r = 0; r < 4; ++r) {
                    const float inv = 1.f / accL[qg][r];
                    const int gq = qs + qg * 16 + quad * 4 + r;
                    unsigned short* ob = O + (size_t)(b * S + gq) * D_MODEL + h * D_K;
                    #pragma unroll
                    for (int dt = 0; dt < 4; ++dt)
                        ob[dt * 16 + l16] = f2bf(accO[qg][dt][r] * inv);
                }
            }
        }
        __syncthreads();   // red dead before next sel's staging
    }
}

// ---------------------------------------------------------------------------
extern "C" void kernel_launch(void* const* d_in, const int* in_sizes, int n_in,
                              void* d_out, int out_size, void* d_ws, size_t ws_size,
                              hipStream_t stream) {
    const float* query = (const float*)d_in[0];
    const float* key   = (const float*)d_in[1];
    const float* value = (const float*)d_in[2];
    const int*   mask  = (const int*)d_in[3];
    const float* Wq = (const float*)d_in[4];
    const float* bq = (const float*)d_in[5];
    const float* Wk = (const float*)d_in[6];
    const float* bk = (const float*)d_in[7];
    const float* Wv = (const float*)d_in[8];
    const float* bv = (const float*)d_in[9];
    const float* Wo = (const float*)d_in[10];
    const float* bo = (const float*)d_in[11];

    const int B  = 2;
    const int BS = in_sizes[3];
    const int S  = BS / B;
    const int M  = BS;

    unsigned short* Qp  = (unsigned short*)d_ws;
    unsigned short* Kp  = Qp  + (size_t)M * D_MODEL;
    unsigned short* VpT = Kp  + (size_t)M * D_MODEL;
    unsigned short* Obf = VpT + (size_t)M * D_MODEL;  // qa staging, then O
    unsigned short* Wbf = Obf + (size_t)M * D_MODEL;
    unsigned short* Wqb = Wbf;
    unsigned short* Wkb = Wbf + (size_t)W_ELEMS;
    unsigned short* Wvb = Wbf + (size_t)W_ELEMS * 2;
    unsigned short* Wob = Wbf + (size_t)W_ELEMS * 3;
    // d_out (25.2 MB fp32) doubles as scratch for ka/va bf16 until final GEMM
    unsigned short* ka = (unsigned short*)d_out;
    unsigned short* va = ka + (size_t)M * D_MODEL;

    dim3 blk(256);
    convert_w4<<<dim3(W_ELEMS / 1024, 4), blk, 0, stream>>>(Wq, Wk, Wv, Wo, Wbf);
    convert_a3<<<dim3((M * D_MODEL) / 1024, 3), blk, 0, stream>>>(
        query, key, value, Obf, ka, va);

    gemm128<true><<<dim3(M / 128, D_MODEL / 128, 3), blk, 0, stream>>>(
        Obf, ka, va, Wqb, Wkb, Wvb, bq, bk, bv, Qp, Kp, VpT, S);

    flash_attn<<<768, blk, 0, stream>>>(Qp, Kp, VpT, mask, Obf, S);

    gemm128<false><<<dim3(M / 128, D_MODEL / 128, 1), blk, 0, stream>>>(
        Obf, Obf, Obf, Wob, Wob, Wob, bo, bo, bo,
        d_out, d_out, d_out, S);
}